// Round 3
// baseline (107.208 us; speedup 1.0000x reference)
//
#include <hip/hip_runtime.h>

typedef float v2f __attribute__((ext_vector_type(2)));
typedef float v4f __attribute__((ext_vector_type(4)));

#define IMG 512
#define NB  8
#define TS  32

// A: h tile [52][56], gy = y0-10+r, gx = x0-12+c   (later overlaid by E [42][52])
#define A_ROWS 52
#define A_STR  56
// BT: transposed convY(h) [56][46]: BT[c][by], gx = x0-12+c, gy = y0-5+by (by 0..41)
#define BT_STR 46
// E: [42][52]: gy = y0-5+ey, gx = x0-5+ex (ex 0..41), overlays Abuf
#define E_STR  52
// CT: transposed convY(E) [42][34]: CT[ex][oy], gx = x0-5+ex, gy = y0+oy, overlays Bbuf
#define CT_STR 34

__device__ __forceinline__ v2f lo2(v4f v) { return __builtin_shufflevector(v, v, 0, 1); }
__device__ __forceinline__ v2f hi2(v4f v) { return __builtin_shufflevector(v, v, 2, 3); }

__global__ __launch_bounds__(256, 6) void marl_fused(
    const float* __restrict__ prob,
    const float* __restrict__ cmap,
    const float* __restrict__ hmap,
    float* __restrict__ out)
{
    __shared__ __align__(16) float Abuf[A_ROWS * A_STR];  // 2912 f
    __shared__ __align__(16) float Bbuf[56 * BT_STR];     // 2576 f
    __shared__ float red[4];

    // normalized 11-tap gaussian (sigma=2) as literals (exact to ~1e-7 rel)
    const float W[11] = {0.00881223f, 0.02714358f, 0.06511405f, 0.12164908f,
                         0.17699840f, 0.20056542f, 0.17699840f, 0.12164908f,
                         0.06511405f, 0.02714358f, 0.00881223f};
    v2f wv[11];
#pragma unroll
    for (int i = 0; i < 11; ++i) wv[i] = (v2f){W[i], W[i]};
    float w2 = 0.f;
#pragma unroll
    for (int i = 0; i < 11; ++i) w2 += W[i] * W[i];
    const float sumk2 = w2 * w2;   // sum of 2-D kernel squared

    const int tid = threadIdx.x;
    const int x0  = blockIdx.x * TS;
    const int y0  = blockIdx.y * TS;
    const size_t base = (size_t)blockIdx.z * (IMG * IMG);

    // ---- P0: load h tile 52x56 (float4, zero-pad OOB) ----
    for (int t = tid; t < 52 * 14; t += 256) {
        int r = t / 14, q = t - r * 14;
        int gy = y0 - 10 + r, gx0 = x0 - 12 + 4 * q;
        v4f v = {0.f, 0.f, 0.f, 0.f};
        if ((unsigned)gy < IMG) {
            const float* hr = &hmap[base + (size_t)gy * IMG];
            if (gx0 >= 0 && gx0 + 3 < IMG) {
                v = *(const v4f*)&hr[gx0];
            } else {
                if ((unsigned)(gx0 + 0) < IMG) v.x = hr[gx0 + 0];
                if ((unsigned)(gx0 + 1) < IMG) v.y = hr[gx0 + 1];
                if ((unsigned)(gx0 + 2) < IMG) v.z = hr[gx0 + 2];
                if ((unsigned)(gx0 + 3) < IMG) v.w = hr[gx0 + 3];
            }
        }
        *(v4f*)&Abuf[r * A_STR + 4 * q] = v;
    }
    __syncthreads();

    // ---- P1: convY(h): A[52][56] -> BT[56][46] (transposed write) ----
    // out rows by 0..41 (gy=y0-5+by), all 56 cols; packed pairs along x
    if (tid < 196) {
        int q = tid % 14, run = tid / 14;     // 14 col-quads x 14 row-runs (R=3)
        int by0 = 3 * run;
        v2f z = {0.f, 0.f};
        v2f accLo[3] = {z, z, z}, accHi[3] = {z, z, z};
#pragma unroll
        for (int i = 0; i < 13; ++i) {
            v4f a = *(const v4f*)&Abuf[(by0 + i) * A_STR + 4 * q];
            v2f lo = lo2(a), hi = hi2(a);
#pragma unroll
            for (int r = 0; r < 3; ++r) {
                int j = i - r;
                if (j >= 0 && j < 11) { accLo[r] += wv[j] * lo; accHi[r] += wv[j] * hi; }
            }
        }
#pragma unroll
        for (int r = 0; r < 3; ++r) {
            int by = by0 + r;
            Bbuf[(4 * q + 0) * BT_STR + by] = accLo[r].x;
            Bbuf[(4 * q + 1) * BT_STR + by] = accLo[r].y;
            Bbuf[(4 * q + 2) * BT_STR + by] = accHi[r].x;
            Bbuf[(4 * q + 3) * BT_STR + by] = accHi[r].y;
        }
    }
    __syncthreads();

    // ---- P2: convX + c-subtract -> E[42][52] (overlays Abuf), zero outside image ----
    // E(ey,ex): tap j reads BT[ex+j+2][ey]; packed vertical pair (ey0, ey0+1)
    if (tid < 231) {
        int p = tid % 21, eq = tid / 21;      // p: ey-pair, eq: ex-quad (0..10)
        int ex0 = 4 * eq, ey0 = 2 * p;
        v2f z = {0.f, 0.f};
        v2f acc[4] = {z, z, z, z};
#pragma unroll
        for (int i = 0; i < 14; ++i) {
            v2f b = *(const v2f*)&Bbuf[(ex0 + 2 + i) * BT_STR + ey0];
#pragma unroll
            for (int c = 0; c < 4; ++c) {
                int j = i - c;
                if (j >= 0 && j < 11) acc[c] += wv[j] * b;
            }
        }
#pragma unroll
        for (int c = 0; c < 4; ++c) {
            int ex = ex0 + c;
            if (ex < 42) {
                int gx = x0 - 5 + ex;
                bool xin = (unsigned)gx < IMG;
#pragma unroll
                for (int h = 0; h < 2; ++h) {
                    int gy = y0 - 5 + ey0 + h;
                    float v = 0.f;
                    if (xin && (unsigned)gy < IMG)
                        v = acc[c][h] - cmap[base + (size_t)gy * IMG + gx];
                    Abuf[(ey0 + h) * E_STR + ex] = v;
                }
            }
        }
    }
    __syncthreads();

    // ---- P3: convY(E) -> CT[42][34] (transposed write, overlays Bbuf) ----
    // out rows oy 0..31, cols ex 0..41; taps E rows oy..oy+10
    if (tid < 176) {
        int eq = tid % 11, run = tid / 11;    // 11 ex-quads x 16 oy-runs (R=2)
        int ex0 = 4 * eq, oy0 = 2 * run;
        v2f z = {0.f, 0.f};
        v2f accLo[2] = {z, z}, accHi[2] = {z, z};
#pragma unroll
        for (int i = 0; i < 12; ++i) {
            v4f e = *(const v4f*)&Abuf[(oy0 + i) * E_STR + ex0];
            v2f lo = lo2(e), hi = hi2(e);
#pragma unroll
            for (int r = 0; r < 2; ++r) {
                int j = i - r;
                if (j >= 0 && j < 11) { accLo[r] += wv[j] * lo; accHi[r] += wv[j] * hi; }
            }
        }
#pragma unroll
        for (int r = 0; r < 2; ++r) {
            int oy = oy0 + r;
            Bbuf[(ex0 + 0) * CT_STR + oy] = accLo[r].x;
            Bbuf[(ex0 + 1) * CT_STR + oy] = accLo[r].y;
            if (ex0 + 2 < 42) {
                Bbuf[(ex0 + 2) * CT_STR + oy] = accHi[r].x;
                Bbuf[(ex0 + 3) * CT_STR + oy] = accHi[r].y;
            }
        }
    }
    __syncthreads();

    // ---- P4: convX -> corr, fused epilogue; packed vertical pair (oy0, oy0+1) ----
    float partial = 0.f;
    {
        int p = tid % 16, oxh = tid / 16;
        int oy0 = 2 * p, ox0 = 2 * oxh;
        v2f z = {0.f, 0.f};
        v2f acc[2] = {z, z};
#pragma unroll
        for (int i = 0; i < 12; ++i) {
            v2f ct = *(const v2f*)&Bbuf[(ox0 + i) * CT_STR + oy0];
#pragma unroll
            for (int c = 0; c < 2; ++c) {
                int j = i - c;
                if (j >= 0 && j < 11) acc[c] += wv[j] * ct;
            }
        }
#pragma unroll
        for (int h = 0; h < 2; ++h) {
            int gy = y0 + oy0 + h;
            size_t rowb = base + (size_t)gy * IMG + (x0 + ox0);
            v2f hv = *(const v2f*)&hmap[rowb];
            v2f pv = *(const v2f*)&prob[rowb];
#pragma unroll
            for (int c = 0; c < 2; ++c) {
                float h_ = hv[c], p_ = pv[c];
                float logp = __logf(h_ > 0.5f ? p_ + 1e-8f : 1.f - p_ + 1e-8f);
                float delta = 1.f - 2.f * h_;
                partial += (2.f * delta * acc[c][h] + sumk2) * logp;
            }
        }
    }

    // ---- reduction ----
#pragma unroll
    for (int off = 32; off > 0; off >>= 1)
        partial += __shfl_down(partial, off, 64);
    if ((tid & 63) == 0) red[tid >> 6] = partial;
    __syncthreads();
    if (tid == 0) {
        float s = red[0] + red[1] + red[2] + red[3];
        atomicAdd(out, s * -0.125f);   // loss = -sum / B
    }
}

extern "C" void kernel_launch(void* const* d_in, const int* in_sizes, int n_in,
                              void* d_out, int out_size, void* d_ws, size_t ws_size,
                              hipStream_t stream) {
    const float* prob = (const float*)d_in[0];
    const float* cmap = (const float*)d_in[1];
    const float* hmap = (const float*)d_in[2];
    float* out = (float*)d_out;

    hipMemsetAsync(out, 0, sizeof(float), stream);

    dim3 grid(IMG / TS, IMG / TS, NB);  // 16 x 16 x 8
    dim3 block(256);
    marl_fused<<<grid, block, 0, stream>>>(prob, cmap, hmap, out);
}

// Round 4
// 93.690 us; speedup vs baseline: 1.1443x; 1.1443x over previous
//
#include <hip/hip_runtime.h>

typedef float v2f __attribute__((ext_vector_type(2)));
typedef float v4f __attribute__((ext_vector_type(4)));

#define IMG 512
#define TS  32
#define TPB 2                 // tiles per block
#define NBLK 1024             // 2048 tiles / 2

// LDS layouts (floats)
#define A_STR  56             // h tile [52][56]; gy=y0-10+r, gx=x0-12+c
#define BT_STR 46             // BT [56][46]: BT[c][by], by 0..41 (gy=y0-5+by)
#define E_STR  44             // E [42][44]: ey 0..41, ex 0..41; overlays Abuf
#define CT_STR 34             // CT [42][34]: CT[ex][oy], oy 0..31; overlays Bbuf

#define HQUADS 728            // 52 rows * 14 quads

__device__ __forceinline__ v2f lo2(v4f v) { return __builtin_shufflevector(v, v, 0, 1); }
__device__ __forceinline__ v2f hi2(v4f v) { return __builtin_shufflevector(v, v, 2, 3); }

// load one float4 of the h halo tile (zero-padded) for quad index idx
__device__ __forceinline__ v4f ldq(const float* __restrict__ hmap, size_t base,
                                   int x0, int y0, int idx) {
    int r = idx / 14, q = idx - r * 14;
    int gy = y0 - 10 + r, gx0 = x0 - 12 + 4 * q;
    v4f v = {0.f, 0.f, 0.f, 0.f};
    if ((unsigned)gy < IMG) {
        const float* hr = &hmap[base + ((size_t)gy << 9)];
        if (gx0 >= 0 && gx0 + 3 < IMG) {
            v = *(const v4f*)&hr[gx0];
        } else {
            if ((unsigned)(gx0 + 0) < IMG) v.x = hr[gx0 + 0];
            if ((unsigned)(gx0 + 1) < IMG) v.y = hr[gx0 + 1];
            if ((unsigned)(gx0 + 2) < IMG) v.z = hr[gx0 + 2];
            if ((unsigned)(gx0 + 3) < IMG) v.w = hr[gx0 + 3];
        }
    }
    return v;
}

__global__ __launch_bounds__(256, 4) void marl_fused(
    const float* __restrict__ prob,
    const float* __restrict__ cmap,
    const float* __restrict__ hmap,
    float* __restrict__ out)
{
    __shared__ __align__(16) float Abuf[52 * A_STR];   // 2912 f (h tile, then E)
    __shared__ __align__(16) float Bbuf[56 * BT_STR];  // 2576 f (BT, then CT)
    __shared__ float red[4];

    const float W[11] = {0.00881223f, 0.02714358f, 0.06511405f, 0.12164908f,
                         0.17699840f, 0.20056540f, 0.17699840f, 0.12164908f,
                         0.06511405f, 0.02714358f, 0.00881223f};
    v2f wv[11];
#pragma unroll
    for (int i = 0; i < 11; ++i) wv[i] = (v2f){W[i], W[i]};
    float w2 = 0.f;
#pragma unroll
    for (int i = 0; i < 11; ++i) w2 += W[i] * W[i];
    const float sumk2 = w2 * w2;
    const v2f z = {0.f, 0.f};

    const int tid = threadIdx.x;
    const int i0 = tid, i1 = tid + 256, i2 = tid + 512;   // i2 valid iff tid<216
    const int T0 = blockIdx.x * TPB;

    // ---- prologue: load tile T0's h halo into Abuf ----
    {
        int b = T0 >> 8, r8 = T0 & 255;
        int x0 = (r8 & 15) * TS, y0 = (r8 >> 4) * TS;
        size_t base = (size_t)b << 18;
        v4f a = ldq(hmap, base, x0, y0, i0);
        v4f bq = ldq(hmap, base, x0, y0, i1);
        v4f c = (tid < 216) ? ldq(hmap, base, x0, y0, i2) : (v4f){0.f,0.f,0.f,0.f};
        { int r = i0 / 14, q = i0 - r * 14; *(v4f*)&Abuf[r * A_STR + 4 * q] = a; }
        { int r = i1 / 14, q = i1 - r * 14; *(v4f*)&Abuf[r * A_STR + 4 * q] = bq; }
        if (tid < 216) { int r = i2 / 14, q = i2 - r * 14; *(v4f*)&Abuf[r * A_STR + 4 * q] = c; }
    }
    __syncthreads();

    float partial = 0.f;

    for (int t = 0; t < TPB; ++t) {
        const int T = T0 + t;
        const int b = T >> 8, r8 = T & 255;
        const int x0 = (r8 & 15) * TS, y0 = (r8 >> 4) * TS;
        const size_t base = (size_t)b << 18;

        // ---- P1: convY(h): Abuf[52][56] -> BT[56][46] (transposed) ----
        if (tid < 196) {
            int q = tid % 14, run = tid / 14;
            int by0 = 3 * run;
            v2f accLo[3] = {z, z, z}, accHi[3] = {z, z, z};
#pragma unroll
            for (int i = 0; i < 13; ++i) {
                v4f a = *(const v4f*)&Abuf[(by0 + i) * A_STR + 4 * q];
                v2f lo = lo2(a), hi = hi2(a);
#pragma unroll
                for (int r = 0; r < 3; ++r) {
                    int j = i - r;
                    if (j >= 0 && j < 11) { accLo[r] += wv[j] * lo; accHi[r] += wv[j] * hi; }
                }
            }
#pragma unroll
            for (int r = 0; r < 3; ++r) {
                int by = by0 + r;
                Bbuf[(4 * q + 0) * BT_STR + by] = accLo[r].x;
                Bbuf[(4 * q + 1) * BT_STR + by] = accLo[r].y;
                Bbuf[(4 * q + 2) * BT_STR + by] = accHi[r].x;
                Bbuf[(4 * q + 3) * BT_STR + by] = accHi[r].y;
            }
        }
        __syncthreads();

        // ---- P2: convX(BT) - c -> E[42][44] (overlays Abuf); zero outside ----
        // lanes vary ex (coalesced cmap); pairs along ey
        if (tid < 231) {
            int eq = tid % 11, p = tid / 11;     // eq: ex-quad 0..10, p: ey-pair 0..20
            int ex0 = 4 * eq, ey0 = 2 * p;
            v2f acc[4] = {z, z, z, z};
#pragma unroll
            for (int i = 0; i < 14; ++i) {
                v2f bb = *(const v2f*)&Bbuf[(ex0 + 2 + i) * BT_STR + ey0];
#pragma unroll
                for (int c = 0; c < 4; ++c) {
                    int j = i - c;
                    if (j >= 0 && j < 11) acc[c] += wv[j] * bb;
                }
            }
#pragma unroll
            for (int c = 0; c < 4; ++c) {
                int ex = ex0 + c;
                if (ex < 42) {
                    int gx = x0 - 5 + ex;
                    bool xin = (unsigned)gx < IMG;
#pragma unroll
                    for (int h = 0; h < 2; ++h) {
                        int gy = y0 - 5 + ey0 + h;
                        float v = 0.f;
                        if (xin && (unsigned)gy < IMG)
                            v = acc[c][h] - cmap[base + ((size_t)gy << 9) + gx];
                        Abuf[(ey0 + h) * E_STR + ex] = v;
                    }
                }
            }
        }
        __syncthreads();

        // ---- P3: convY(E) -> CT[42][34] (transposed); prefetch next h tile ----
        v4f pf0, pf1, pf2;
        const bool havepf = (t + 1 < TPB);
        int nx0 = 0, ny0 = 0; size_t nbase = 0;
        if (havepf) {
            int Tn = T + 1;
            int nb = Tn >> 8, nr8 = Tn & 255;
            nx0 = (nr8 & 15) * TS; ny0 = (nr8 >> 4) * TS;
            nbase = (size_t)nb << 18;
            pf0 = ldq(hmap, nbase, nx0, ny0, i0);
            pf1 = ldq(hmap, nbase, nx0, ny0, i1);
            if (tid < 216) pf2 = ldq(hmap, nbase, nx0, ny0, i2);
        }
        if (tid < 176) {
            int eq = tid % 11, run = tid / 11;   // 11 ex-quads x 16 oy-runs (2 each)
            int ex0 = 4 * eq, oy0 = 2 * run;
            v2f accLo[2] = {z, z}, accHi[2] = {z, z};
#pragma unroll
            for (int i = 0; i < 12; ++i) {
                v4f e = *(const v4f*)&Abuf[(oy0 + i) * E_STR + ex0];
                v2f lo = lo2(e), hi = hi2(e);
#pragma unroll
                for (int r = 0; r < 2; ++r) {
                    int j = i - r;
                    if (j >= 0 && j < 11) { accLo[r] += wv[j] * lo; accHi[r] += wv[j] * hi; }
                }
            }
#pragma unroll
            for (int r = 0; r < 2; ++r) {
                int oy = oy0 + r;
                Bbuf[(ex0 + 0) * CT_STR + oy] = accLo[r].x;
                Bbuf[(ex0 + 1) * CT_STR + oy] = accLo[r].y;
                if (ex0 + 2 < 42) {
                    Bbuf[(ex0 + 2) * CT_STR + oy] = accHi[r].x;
                    Bbuf[(ex0 + 3) * CT_STR + oy] = accHi[r].y;
                }
            }
        }
        __syncthreads();

        // ---- P4: write prefetched h into Abuf; convX(CT) -> corr + epilogue ----
        if (havepf) {
            { int r = i0 / 14, q = i0 - r * 14; *(v4f*)&Abuf[r * A_STR + 4 * q] = pf0; }
            { int r = i1 / 14, q = i1 - r * 14; *(v4f*)&Abuf[r * A_STR + 4 * q] = pf1; }
            if (tid < 216) { int r = i2 / 14, q = i2 - r * 14; *(v4f*)&Abuf[r * A_STR + 4 * q] = pf2; }
        }
        {
            int oxh = tid % 16, p = tid / 16;    // lanes vary ox (coalesced epilogue)
            int ox0 = 2 * oxh, oy0 = 2 * p;
            v2f acc[2] = {z, z};
#pragma unroll
            for (int i = 0; i < 12; ++i) {
                v2f ct = *(const v2f*)&Bbuf[(ox0 + i) * CT_STR + oy0];
#pragma unroll
                for (int c = 0; c < 2; ++c) {
                    int j = i - c;
                    if (j >= 0 && j < 11) acc[c] += wv[j] * ct;
                }
            }
#pragma unroll
            for (int h = 0; h < 2; ++h) {
                int gy = y0 + oy0 + h;
                size_t rowb = base + ((size_t)gy << 9) + (x0 + ox0);
                v2f hv = *(const v2f*)&hmap[rowb];
                v2f pv = *(const v2f*)&prob[rowb];
#pragma unroll
                for (int c = 0; c < 2; ++c) {
                    float h_ = hv[c], p_ = pv[c];
                    float logp = __logf(h_ > 0.5f ? p_ + 1e-8f : 1.f - p_ + 1e-8f);
                    float delta = 1.f - 2.f * h_;
                    partial += (2.f * delta * acc[c][h] + sumk2) * logp;
                }
            }
        }
        __syncthreads();
    }

    // ---- single reduction + one atomic per block ----
#pragma unroll
    for (int off = 32; off > 0; off >>= 1)
        partial += __shfl_down(partial, off, 64);
    if ((tid & 63) == 0) red[tid >> 6] = partial;
    __syncthreads();
    if (tid == 0) {
        float s = red[0] + red[1] + red[2] + red[3];
        atomicAdd(out, s * -0.125f);   // loss = -sum / B
    }
}

extern "C" void kernel_launch(void* const* d_in, const int* in_sizes, int n_in,
                              void* d_out, int out_size, void* d_ws, size_t ws_size,
                              hipStream_t stream) {
    const float* prob = (const float*)d_in[0];
    const float* cmap = (const float*)d_in[1];
    const float* hmap = (const float*)d_in[2];
    float* out = (float*)d_out;

    hipMemsetAsync(out, 0, sizeof(float), stream);

    marl_fused<<<dim3(NBLK), dim3(256), 0, stream>>>(prob, cmap, hmap, out);
}